// Round 1
// 312.219 us; speedup vs baseline: 1.0330x; 1.0330x over previous
//
#include <hip/hip_runtime.h>
#include <math.h>

#define HWPIX 65536      // 256*256
#define HWQ   16384      // HWPIX/4 (float4 units)
#define HWH   32768      // HWPIX/2 (float2 units)
#define BATCH 64

// beta_coeff  = BETA0*sqrt(M_INV)      = 4.0*2.0  = 8.0
// Gamma_coeff = GAMMA_BIG*sqrt(M_INV)  = 0.04*2.0 = 0.08
// bg_scale    = sqrt(2*8*0.08)         = sqrt(1.28)
#define KBETA   8.0f
#define KBGAMMA 0.64f

typedef float vf2 __attribute__((ext_vector_type(2)));

__device__ __forceinline__ float4 f4_fma(float4 a, float4 b, float4 c) {
    return make_float4(fmaf(a.x, b.x, c.x), fmaf(a.y, b.y, c.y),
                       fmaf(a.z, b.z, c.z), fmaf(a.w, b.w, c.w));
}

// ---------------------------------------------------------------------------
// Kernel 1: partial per-pixel covariance. 8 chunks x 8 batches, float4 pixels.
// grid: 512 blocks x 256 threads. Per-block trace partial (no atomic).
// ---------------------------------------------------------------------------
__global__ __launch_bounds__(256, 2) void k_partialG(const float4* __restrict__ s,
                                                     float4* __restrict__ gpart,
                                                     float* __restrict__ trace_part) {
    int tid   = blockIdx.x * 256 + threadIdx.x;
    int p     = tid & (HWQ - 1);
    int chunk = tid >> 14;          // 0..7
    int b0    = chunk * 8;

    float4 g00 = make_float4(0,0,0,0), g01 = g00, g02 = g00;
    float4 g11 = g00, g12 = g00, g22 = g00;
#pragma unroll
    for (int b = b0; b < b0 + 8; ++b) {
        const float4* base = s + (size_t)b * 3 * HWQ + p;
        float4 s0 = base[0];
        float4 s1 = base[HWQ];
        float4 s2 = base[2 * HWQ];
        g00 = f4_fma(s0, s0, g00); g01 = f4_fma(s0, s1, g01); g02 = f4_fma(s0, s2, g02);
        g11 = f4_fma(s1, s1, g11); g12 = f4_fma(s1, s2, g12); g22 = f4_fma(s2, s2, g22);
    }
    float4* gp = gpart + (size_t)chunk * 6 * HWQ + p;
    gp[0 * HWQ] = g00; gp[1 * HWQ] = g01; gp[2 * HWQ] = g02;
    gp[3 * HWQ] = g11; gp[4 * HWQ] = g12; gp[5 * HWQ] = g22;

    // trace reduction -> one plain store per block (summed lazily in k2)
    float tr = (g00.x + g00.y + g00.z + g00.w)
             + (g11.x + g11.y + g11.z + g11.w)
             + (g22.x + g22.y + g22.z + g22.w);
#pragma unroll
    for (int off = 32; off > 0; off >>= 1) tr += __shfl_down(tr, off, 64);
    __shared__ float sred[4];
    int lane = threadIdx.x & 63;
    int w    = threadIdx.x >> 6;
    if (lane == 0) sred[w] = tr;
    __syncthreads();
    if (threadIdx.x == 0)
        trace_part[blockIdx.x] = sred[0] + sred[1] + sred[2] + sred[3];
}

// ---------------------------------------------------------------------------
// Kernel 2: per-pixel matrices (scalar; tiny). grid: 256 x 256
// emits 27 planes: A1(9)=beta*L*Ginv, A2(6)=-beta*L (lower),
// A3(9)=-beta*Gamma*(G*Ginv), D(3)=bg*rowsum(L)
// ---------------------------------------------------------------------------
__global__ __launch_bounds__(256) void k_matrices(const float* __restrict__ gpart,
                                                  const float* __restrict__ trace_part,
                                                  const float* __restrict__ t,
                                                  float* __restrict__ mats) {
    int p = blockIdx.x * 256 + threadIdx.x;

    float g[6];
#pragma unroll
    for (int k = 0; k < 6; ++k) {
        float v = 0.f;
#pragma unroll
        for (int c = 0; c < 8; ++c)
            v += gpart[(size_t)c * 6 * HWPIX + (size_t)k * HWPIX + p];
        g[k] = v * (1.0f / BATCH);
    }

    float t0   = t[0];
    float norm = 1.0f;
    if (t0 == 1.0f) {             // uniform branch, ~never taken for bench input
        float s = 0.f;
        for (int i = 0; i < 512; ++i) s += trace_part[i];
        float diag_mean = s * (1.0f / (BATCH * (float)HWPIX * 3.0f));
        norm = diag_mean * 4.0f;  // * M_INV
    }
    float alpha = 0.5f * expf(-4.5f * (1.0f - t0));
    float sa    = alpha / norm;
    float idv   = (1.0f - alpha) * 0.25f;     // (1-alpha)/M_INV

    float a = sa * g[0] + idv;
    float b = sa * g[1];
    float c = sa * g[2];
    float d = sa * g[3] + idv;
    float e = sa * g[4];
    float f = sa * g[5] + idv;

    // symmetric inverse via adjugate
    float i00 = d * f - e * e;
    float i01 = c * e - b * f;
    float i02 = b * e - d * c;
    float i11 = a * f - c * c;
    float i12 = b * c - a * e;
    float i22 = a * d - b * b;
    float rdet = 1.0f / (a * i00 + b * i01 + c * i02);
    float v00 = i00 * rdet, v01 = i01 * rdet, v02 = i02 * rdet;
    float v11 = i11 * rdet, v12 = i12 * rdet, v22 = i22 * rdet;

    // Cholesky lower L
    float l00 = sqrtf(a);
    float l10 = b / l00;
    float l20 = c / l00;
    float l11 = sqrtf(d - l10 * l10);
    float l21 = (e - l20 * l10) / l11;
    float l22 = sqrtf(f - l20 * l20 - l21 * l21);

    float m[27];
    m[0] = KBETA * (l00 * v00);
    m[1] = KBETA * (l00 * v01);
    m[2] = KBETA * (l00 * v02);
    m[3] = KBETA * (l10 * v00 + l11 * v01);
    m[4] = KBETA * (l10 * v01 + l11 * v11);
    m[5] = KBETA * (l10 * v02 + l11 * v12);
    m[6] = KBETA * (l20 * v00 + l21 * v01 + l22 * v02);
    m[7] = KBETA * (l20 * v01 + l21 * v11 + l22 * v12);
    m[8] = KBETA * (l20 * v02 + l21 * v12 + l22 * v22);
    m[9]  = -KBETA * l00;
    m[10] = -KBETA * l10;
    m[11] = -KBETA * l11;
    m[12] = -KBETA * l20;
    m[13] = -KBETA * l21;
    m[14] = -KBETA * l22;
    m[15] = -KBGAMMA * (a * v00 + b * v01 + c * v02);
    m[16] = -KBGAMMA * (a * v01 + b * v11 + c * v12);
    m[17] = -KBGAMMA * (a * v02 + b * v12 + c * v22);
    m[18] = -KBGAMMA * (b * v00 + d * v01 + e * v02);
    m[19] = -KBGAMMA * (b * v01 + d * v11 + e * v12);
    m[20] = -KBGAMMA * (b * v02 + d * v12 + e * v22);
    m[21] = -KBGAMMA * (c * v00 + e * v01 + f * v02);
    m[22] = -KBGAMMA * (c * v01 + e * v11 + f * v12);
    m[23] = -KBGAMMA * (c * v02 + e * v12 + f * v22);
    const float bg = 1.13137084989847603904f;  // sqrt(1.28)
    m[24] = bg * l00;
    m[25] = bg * (l10 + l11);
    m[26] = bg * (l20 + l21 + l22);

#pragma unroll
    for (int k = 0; k < 27; ++k)
        mats[(size_t)k * HWPIX + p] = m[k];
}

// ---------------------------------------------------------------------------
// Kernel 3: streaming apply, float2 pixels (halves m[] VGPR footprint vs f4).
// grid: 1024 x 256 (262144 threads); each thread: one f2-pixel x 8 batches.
// Nontemporal on the 300 MB of streaming traffic; mats stays L2-resident.
// ---------------------------------------------------------------------------
__global__ __launch_bounds__(256, 3) void k_apply(const vf2* __restrict__ u,
                                                  const vf2* __restrict__ mats,
                                                  vf2* __restrict__ out) {
    int tid = blockIdx.x * 256 + threadIdx.x;
    int p   = tid & (HWH - 1);
    int bq  = tid >> 15;            // 0..7

    vf2 m[27];
#pragma unroll
    for (int k = 0; k < 27; ++k) m[k] = mats[(size_t)k * HWH + p];

    vf2* drift = out;
    vf2* diff  = out + (size_t)BATCH * 6 * HWH;
    vf2 z = {0.0f, 0.0f};

#pragma unroll 2
    for (int b = bq * 8; b < bq * 8 + 8; ++b) {
        const vf2* ub = u + (size_t)b * 6 * HWH + p;
        vf2 x0 = __builtin_nontemporal_load(ub + 0 * HWH);
        vf2 x1 = __builtin_nontemporal_load(ub + 1 * HWH);
        vf2 x2 = __builtin_nontemporal_load(ub + 2 * HWH);
        vf2 r0 = __builtin_nontemporal_load(ub + 3 * HWH);
        vf2 r1 = __builtin_nontemporal_load(ub + 4 * HWH);
        vf2 r2 = __builtin_nontemporal_load(ub + 5 * HWH);

        vf2 dx0 = m[0] * r0 + m[1] * r1 + m[2] * r2;
        vf2 dx1 = m[3] * r0 + m[4] * r1 + m[5] * r2;
        vf2 dx2 = m[6] * r0 + m[7] * r1 + m[8] * r2;
        vf2 dr0 = m[9]  * x0 + m[15] * r0 + m[16] * r1 + m[17] * r2;
        vf2 dr1 = m[10] * x0 + m[11] * x1
                + m[18] * r0 + m[19] * r1 + m[20] * r2;
        vf2 dr2 = m[12] * x0 + m[13] * x1 + m[14] * x2
                + m[21] * r0 + m[22] * r1 + m[23] * r2;

        vf2* db = drift + (size_t)b * 6 * HWH + p;
        __builtin_nontemporal_store(dx0, db + 0 * HWH);
        __builtin_nontemporal_store(dx1, db + 1 * HWH);
        __builtin_nontemporal_store(dx2, db + 2 * HWH);
        __builtin_nontemporal_store(dr0, db + 3 * HWH);
        __builtin_nontemporal_store(dr1, db + 4 * HWH);
        __builtin_nontemporal_store(dr2, db + 5 * HWH);

        vf2* fb = diff + (size_t)b * 6 * HWH + p;
        __builtin_nontemporal_store(z,     fb + 0 * HWH);
        __builtin_nontemporal_store(z,     fb + 1 * HWH);
        __builtin_nontemporal_store(z,     fb + 2 * HWH);
        __builtin_nontemporal_store(m[24], fb + 3 * HWH);
        __builtin_nontemporal_store(m[25], fb + 4 * HWH);
        __builtin_nontemporal_store(m[26], fb + 5 * HWH);
    }
}

extern "C" void kernel_launch(void* const* d_in, const int* in_sizes, int n_in,
                              void* d_out, int out_size, void* d_ws, size_t ws_size,
                              hipStream_t stream) {
    const float* u  = (const float*)d_in[0];
    const float* sx = (const float*)d_in[1];
    const float* t  = (const float*)d_in[2];
    float* out = (float*)d_out;
    float* ws  = (float*)d_ws;

    float* gpart      = ws;                              // 8*6*65536 floats = 12.6 MB
    float* trace_part = ws + (size_t)8 * 6 * HWPIX;      // 512 floats
    float* mats       = trace_part + 512;                // 27*65536 floats = 7.1 MB

    k_partialG<<<512, 256, 0, stream>>>((const float4*)sx, (float4*)gpart, trace_part);
    k_matrices<<<256, 256, 0, stream>>>(gpart, trace_part, t, mats);
    k_apply<<<1024, 256, 0, stream>>>((const vf2*)u, (const vf2*)mats, (vf2*)out);
}